// Round 2
// baseline (23838.792 us; speedup 1.0000x reference)
//
#include <hip/hip_runtime.h>
#include <hip/hip_bf16.h>
#include <math.h>

// Autoregressive LSTM + Gaussian heads. B=256 independent rows -> one block/row.
// Runtime dtype detection: harness may hand us fp32 or bf16 buffers; a probe
// kernel inspects the bias buffer's bit patterns and sets a flag in d_ws.
// Two templated main kernels launch; each runs only if the flag matches.

#define BATCH 256
#define SEQT  1024
#define DX    128
#define DZ    128
#define UNITS 256
#define G4    1024  // 4*UNITS

__device__ __forceinline__ float ldf(const float* p) { return *p; }
__device__ __forceinline__ float ldf(const __hip_bfloat16* p) { return __bfloat162float(*p); }
__device__ __forceinline__ void stf(float* p, float v) { *p = v; }
__device__ __forceinline__ void stf(__hip_bfloat16* p, float v) { *p = __float2bfloat16(v); }

__device__ __forceinline__ float sigmoidf_(float x) { return 1.0f / (1.0f + expf(-x)); }
__device__ __forceinline__ float softplusf_(float x) {
    float ax = fabsf(x);
    return fmaxf(x, 0.0f) + log1pf(expf(-ax));
}

// Probe: bias holds 1024 small values (|v| <= ~0.3). If the buffer is bf16,
// every 16-bit word has exponent < 127. If it is fp32, the first 1024 words
// cover 512 floats whose low-mantissa words are ~random -> some word has
// exponent >= 127 with probability 1 - 0.5^512. flag=1 => fp32 data.
__global__ void detect_dtype_kernel(const unsigned short* __restrict__ bias_words,
                                    int* __restrict__ flag) {
    __shared__ int any_big;
    if (threadIdx.x == 0) any_big = 0;
    __syncthreads();
    int local = 0;
    for (int i = threadIdx.x; i < 1024; i += 256) {
        unsigned short w = bias_words[i];
        int e = (w >> 7) & 0xFF;
        if (e >= 127) local = 1;
    }
    if (local) atomicOr(&any_big, 1);
    __syncthreads();
    if (threadIdx.x == 0) flag[0] = any_big;
}

template <typename T>
__global__ __launch_bounds__(256) void lstm_ar_kernel(
    const int* __restrict__ flag, int want,
    const T* __restrict__ inp,   // [B][T][DX]
    const T* __restrict__ K,     // [256][1024] gate cols: i,f,g,o blocks of 256
    const T* __restrict__ R,     // [256][1024]
    const T* __restrict__ bias,  // [1024]
    const T* __restrict__ Wmu,   // [256][128]
    const T* __restrict__ bmu,   // [128]
    const T* __restrict__ Wsig,  // [256][128]
    const T* __restrict__ bsig,  // [128]
    const T* __restrict__ eps,   // [T-1][B][DZ]
    T* __restrict__ out)         // mu [B][T][DZ] then sigma [B][T][DZ]
{
    if (flag[0] != want) return;

    const int b = blockIdx.x;    // batch row
    const int u = threadIdx.x;   // 0..255: gate-unit index

    __shared__ float zx_s[256];  // [ z(128) | x(128) ]
    __shared__ float h_s[256];
    __shared__ float mu_s[128];
    __shared__ float sg_s[128];

    float c = 0.0f;

    const float b_i = ldf(bias + u);
    const float b_f = ldf(bias + 256 + u);
    const float b_g = ldf(bias + 512 + u);
    const float b_o = ldf(bias + 768 + u);
    const float b_head = (u < 128) ? ldf(bmu + u) : ldf(bsig + (u - 128));

    zx_s[u] = 0.0f;
    h_s[u] = 0.0f;
    __syncthreads();
    if (u < 128) {
        zx_s[128 + u] = ldf(inp + ((size_t)b * SEQT + 0) * DX + u);
    }
    __syncthreads();

    const size_t out_sig_off = (size_t)BATCH * SEQT * DZ;

    for (int t = 0; t < SEQT; ++t) {
        // ---- gates: thread u computes columns u, 256+u, 512+u, 768+u ----
        float ai = b_i, af = b_f, ag = b_g, ao = b_o;
        {
            const T* kp = K + u;
            #pragma unroll 8
            for (int i = 0; i < 256; ++i) {
                const float a = zx_s[i];
                ai += a * ldf(kp);
                af += a * ldf(kp + 256);
                ag += a * ldf(kp + 512);
                ao += a * ldf(kp + 768);
                kp += G4;
            }
        }
        {
            const T* rp = R + u;
            #pragma unroll 8
            for (int i = 0; i < 256; ++i) {
                const float a = h_s[i];
                ai += a * ldf(rp);
                af += a * ldf(rp + 256);
                ag += a * ldf(rp + 512);
                ao += a * ldf(rp + 768);
                rp += G4;
            }
        }

        const float gi = sigmoidf_(ai);
        const float gf = sigmoidf_(af);
        const float gg = tanhf(ag);
        const float go = sigmoidf_(ao);
        c = gf * c + gi * gg;
        const float hn = go * tanhf(c);

        __syncthreads();       // all reads of old h_s / zx_s done
        h_s[u] = hn;
        __syncthreads();       // new h visible

        // ---- heads: threads 0..127 -> mu, 128..255 -> sigma ----
        float acc = b_head;
        if (u < 128) {
            const T* wp = Wmu + u;
            #pragma unroll 8
            for (int k = 0; k < 256; ++k) {
                acc += h_s[k] * ldf(wp);
                wp += DZ;
            }
            mu_s[u] = acc;
            stf(out + ((size_t)b * SEQT + t) * DZ + u, acc);
        } else {
            const int d = u - 128;
            const T* wp = Wsig + d;
            #pragma unroll 8
            for (int k = 0; k < 256; ++k) {
                acc += h_s[k] * ldf(wp);
                wp += DZ;
            }
            const float sg = softplusf_(acc) + 1e-6f;
            sg_s[d] = sg;
            stf(out + out_sig_off + ((size_t)b * SEQT + t) * DZ + d, sg);
        }
        __syncthreads();       // mu_s / sg_s visible

        // ---- prepare zx for next step ----
        if (t < SEQT - 1) {
            if (u < 128) {
                const float e = ldf(eps + ((size_t)t * BATCH + b) * DZ + u);
                zx_s[u] = mu_s[u] + sg_s[u] * e;   // reparameterized sample
                zx_s[128 + u] = ldf(inp + ((size_t)b * SEQT + (t + 1)) * DX + u);
            }
        }
        __syncthreads();
    }
}

template <typename T>
static void launch_main(const int* flag, int want, void* const* d_in, void* d_out,
                        hipStream_t stream) {
    lstm_ar_kernel<T><<<BATCH, 256, 0, stream>>>(
        flag, want,
        (const T*)d_in[0], (const T*)d_in[1], (const T*)d_in[2], (const T*)d_in[3],
        (const T*)d_in[4], (const T*)d_in[5], (const T*)d_in[6], (const T*)d_in[7],
        (const T*)d_in[8], (T*)d_out);
}

extern "C" void kernel_launch(void* const* d_in, const int* in_sizes, int n_in,
                              void* d_out, int out_size, void* d_ws, size_t ws_size,
                              hipStream_t stream) {
    int* flag = (int*)d_ws;   // d_ws is re-poisoned each call; probe rewrites it
    detect_dtype_kernel<<<1, 256, 0, stream>>>((const unsigned short*)d_in[3], flag);
    launch_main<__hip_bfloat16>(flag, 0, d_in, d_out, stream);
    launch_main<float>(flag, 1, d_in, d_out, stream);
}